// Round 5
// baseline (541.473 us; speedup 1.0000x reference)
//
#include <hip/hip_runtime.h>
#include <hip/hip_cooperative_groups.h>
#include <math.h>

namespace cg = cooperative_groups;

namespace {

constexpr int B  = 16;
constexpr int S  = 1024;
constexpr int H  = 768;
constexpr int NH = 12;
constexpr int DH = 64;
constexpr int FF = 3072;
constexpr int GRID = 256;
constexpr int BLK  = 256;
constexpr float EPS = 1e-12f;

struct MegaParams {
    const float *x, *mask, *wq, *bq, *wk, *bk, *wv, *bv, *wo, *bo,
                *ln1g, *ln1b, *w1, *b1, *w2, *b2, *ln2g, *ln2b,
                *wp, *bp, *wm, *bm;
    float* out;
    float *q0_part, *u, *constk, *psum, *xpart, *ctx_part, *wo_part,
          *attn_out, *ffn1_part, *ffn2_part, *hidden, *pool_part;
};

__device__ __forceinline__ float waveReduceSum(float v) {
#pragma unroll
    for (int d = 1; d < 64; d <<= 1) v += __shfl_xor(v, d);
    return v;
}

// 256-thread block reduce; red = 4 floats of shared
__device__ __forceinline__ float blockReduce256(float v, float* red) {
    const int lane = threadIdx.x & 63, wid = threadIdx.x >> 6;
    v = waveReduceSum(v);
    __syncthreads();
    if (lane == 0) red[wid] = v;
    __syncthreads();
    return red[0] + red[1] + red[2] + red[3];
}

// ===== P0: q0_part[sp][b][j] = x[:,0,:] @ wq  (288 vblocks) =================
__device__ void phase0(const MegaParams& p, float* smem, int bx, int tid) {
    for (int vb = bx; vb < 288; vb += GRID) {
        const int jt = vb % 12, sp = vb / 12, i0 = sp * 32;
        __syncthreads();
        float* Asl = smem;
        for (int e = tid; e < 512; e += BLK) {
            const int b = e >> 5, ii = e & 31;
            Asl[e] = p.x[(size_t)b * S * H + i0 + ii];
        }
        __syncthreads();
        const int jl = tid & 63, bg = tid >> 6, j = jt * 64 + jl;
        const float* wp_ = p.wq + (size_t)i0 * H + j;
        float a0 = 0, a1 = 0, a2 = 0, a3 = 0;
#pragma unroll
        for (int ii = 0; ii < 32; ++ii) {
            const float w = wp_[(size_t)ii * H];
            a0 += w * Asl[(bg * 4 + 0) * 32 + ii];
            a1 += w * Asl[(bg * 4 + 1) * 32 + ii];
            a2 += w * Asl[(bg * 4 + 2) * 32 + ii];
            a3 += w * Asl[(bg * 4 + 3) * 32 + ii];
        }
        float* pp = p.q0_part + ((size_t)sp * B) * H + j;
        pp[(size_t)(bg * 4 + 0) * H] = a0;
        pp[(size_t)(bg * 4 + 1) * H] = a1;
        pp[(size_t)(bg * 4 + 2) * H] = a2;
        pp[(size_t)(bg * 4 + 3) * H] = a3;
    }
}

// ===== P1: u[b,h,:] = wk_head @ q0_head ; constk = bk_h·q0_h  (192 blocks) ==
__device__ void phase1(const MegaParams& p, float* smem, int bx, int tid) {
    if (bx >= B * NH) return_void: ;
    if (bx < B * NH) {
        const int b = bx / NH, h = bx % NH;
        float* qh = smem;
        if (tid < DH) {
            float v = p.bq[h * DH + tid];
#pragma unroll
            for (int sp = 0; sp < 24; ++sp)
                v += p.q0_part[((size_t)sp * B + b) * H + h * DH + tid];
            qh[tid] = v;
        }
        __syncthreads();
        if (tid < DH) {
            float v = p.bk[h * DH + tid] * qh[tid];
            v = waveReduceSum(v);
            if (tid == 0) p.constk[b * NH + h] = v;
        }
        const int jj = tid & 3, iq = tid >> 2;
        const float4* qv = (const float4*)qh;
        float4 q4[4];
#pragma unroll
        for (int c = 0; c < 4; ++c) q4[c] = qv[jj * 4 + c];
#pragma unroll 4
        for (int ir = 0; ir < 12; ++ir) {
            const int i = ir * 64 + iq;
            const float4* wr = (const float4*)(p.wk + (size_t)i * H + h * DH);
            float s = 0.f;
#pragma unroll
            for (int c = 0; c < 4; ++c) {
                const float4 w = wr[jj * 4 + c];
                s += w.x * q4[c].x + w.y * q4[c].y + w.z * q4[c].z + w.w * q4[c].w;
            }
            s += __shfl_xor(s, 1);
            s += __shfl_xor(s, 2);
            if (jj == 0) p.u[((size_t)(b * NH + h)) * H + i] = s;
        }
    }
}

// ===== P2: fused score(exp)+psum+xbar partial. block: b=bx&15, kt0=bx>>4,
//           handles kt0 and kt0+16; xpart slot kt0 (16 slots). ===============
__device__ void phase2(const MegaParams& p, float* smem, int bx, int tid) {
    const int b = bx & 15, kt0 = bx >> 4;
    float* ul   = smem;                 // 9216
    float* e_sh = smem + 9216;          // 384 = 32 k x 12 h
    float* ck   = smem + 9600;          // 12
    float (*wsum)[NH] = (float(*)[NH])(smem + 9612);  // 4 x 12
    {
        const float4* ug = (const float4*)(p.u + (size_t)b * NH * H);
        float4* ul4 = (float4*)ul;
        for (int e = tid; e < NH * H / 4; e += BLK) ul4[e] = ug[e];
        if (tid < NH) ck[tid] = p.constk[b * NH + tid];
    }
    float aB0[NH], aB1[NH], aB2[NH];
#pragma unroll
    for (int h = 0; h < NH; ++h) { aB0[h] = 0.f; aB1[h] = 0.f; aB2[h] = 0.f; }
    const int jj = tid & 15, kk = tid >> 4;
    const float4* ul4 = (const float4*)ul;

    for (int it = 0; it < 2; ++it) {
        const int kt = kt0 + it * 16;
        __syncthreads();   // it0: ul ready; it1: e_sh/wsum WAR protection
        const int k0 = kt * 32 + kk * 2;
        float4 xv0[12], xv1[12];
        {
            const float4* xr0 = (const float4*)(p.x + ((size_t)b * S + k0) * H);
            const float4* xr1 = (const float4*)(p.x + ((size_t)b * S + k0 + 1) * H);
#pragma unroll
            for (int t = 0; t < 12; ++t) { xv0[t] = xr0[jj + 16 * t]; xv1[t] = xr1[jj + 16 * t]; }
        }
        float acc0[NH], acc1[NH];
#pragma unroll
        for (int h = 0; h < NH; ++h) {
            float a0 = 0.f, a1 = 0.f;
#pragma unroll
            for (int t = 0; t < 12; ++t) {
                const float4 uv = ul4[h * 192 + jj + 16 * t];
                a0 += xv0[t].x * uv.x + xv0[t].y * uv.y + xv0[t].z * uv.z + xv0[t].w * uv.w;
                a1 += xv1[t].x * uv.x + xv1[t].y * uv.y + xv1[t].z * uv.z + xv1[t].w * uv.w;
            }
            acc0[h] = a0; acc1[h] = a1;
        }
#pragma unroll
        for (int h = 0; h < NH; ++h) {
#pragma unroll
            for (int d = 1; d < 16; d <<= 1) {
                acc0[h] += __shfl_xor(acc0[h], d);
                acc1[h] += __shfl_xor(acc1[h], d);
            }
        }
        const float mk0 = p.mask[b * S + k0];
        const float mk1 = p.mask[b * S + k0 + 1];
        float e0[NH], e1[NH], ps[NH];
#pragma unroll
        for (int h = 0; h < NH; ++h) {
            e0[h] = expf(acc0[h] * 0.125f + ck[h] + mk0);
            e1[h] = expf(acc1[h] * 0.125f + ck[h] + mk1);
            ps[h] = e0[h] + e1[h];
        }
        if (jj == 0) {
#pragma unroll
            for (int h = 0; h < NH; ++h) {
                e_sh[(kk * 2) * NH + h]     = e0[h];
                e_sh[(kk * 2 + 1) * NH + h] = e1[h];
            }
        }
#pragma unroll
        for (int h = 0; h < NH; ++h) {
            ps[h] += __shfl_xor(ps[h], 16);
            ps[h] += __shfl_xor(ps[h], 32);
        }
        const int wid = tid >> 6;
        if ((tid & 63) == 0) {
#pragma unroll
            for (int h = 0; h < NH; ++h) wsum[wid][h] = ps[h];
        }
        __syncthreads();
        if (tid < NH)
            p.psum[((size_t)(b * 32 + kt)) * NH + tid] =
                wsum[0][tid] + wsum[1][tid] + wsum[2][tid] + wsum[3][tid];

        // phase B: accumulate unnormalized xbar partial (x rows L1/L2-hot)
        const float* xr = p.x + ((size_t)b * S + kt * 32) * H;
#pragma unroll 2
        for (int k = 0; k < 32; ++k) {
            const float x0 = xr[(size_t)k * H + tid];
            const float x1 = xr[(size_t)k * H + tid + 256];
            const float x2 = xr[(size_t)k * H + tid + 512];
#pragma unroll
            for (int h = 0; h < NH; ++h) {
                const float ev = e_sh[k * NH + h];
                aB0[h] += ev * x0; aB1[h] += ev * x1; aB2[h] += ev * x2;
            }
        }
    }
    float* op = p.xpart + ((size_t)(b * 16 + kt0)) * NH * H;
#pragma unroll
    for (int h = 0; h < NH; ++h) {
        op[(size_t)h * H + tid]       = aB0[h];
        op[(size_t)h * H + tid + 256] = aB1[h];
        op[(size_t)h * H + tid + 512] = aB2[h];
    }
}

// ===== P3: ctx_part = (sum_16 xpart) * rinv @ wv_head  (288 vblocks) ========
__device__ void phase3(const MegaParams& p, float* smem, int bx, int tid) {
    for (int vb = bx; vb < 288; vb += GRID) {
        const int jt = vb % 12, sp = vb / 12, i0 = sp * 32;   // jt = head
        __syncthreads();
        float* Asl  = smem;
        float* rinv = smem + 1024;
        if (tid < B) {
            float s = 0.f;
#pragma unroll
            for (int kt = 0; kt < 32; ++kt)
                s += p.psum[((size_t)(tid * 32 + kt)) * NH + jt];
            rinv[tid] = 1.0f / s;
        }
        for (int e = tid; e < 512; e += BLK) {
            const int b = e >> 5, ii = e & 31;
            float v = 0.f;
#pragma unroll
            for (int s2 = 0; s2 < 16; ++s2)
                v += p.xpart[((size_t)(b * 16 + s2)) * NH * H + (size_t)jt * H + i0 + ii];
            Asl[e] = v;
        }
        __syncthreads();
        const int jl = tid & 63, bg = tid >> 6;
        const int j = jt * 64 + jl;
        const float* wp_ = p.wv + (size_t)i0 * H + j;
        float a0 = 0, a1 = 0, a2 = 0, a3 = 0;
#pragma unroll
        for (int ii = 0; ii < 32; ++ii) {
            const float w = wp_[(size_t)ii * H];
            a0 += w * Asl[(bg * 4 + 0) * 32 + ii];
            a1 += w * Asl[(bg * 4 + 1) * 32 + ii];
            a2 += w * Asl[(bg * 4 + 2) * 32 + ii];
            a3 += w * Asl[(bg * 4 + 3) * 32 + ii];
        }
        float* pp = p.ctx_part + ((size_t)sp * B) * H + j;
        pp[(size_t)(bg * 4 + 0) * H] = a0 * rinv[bg * 4 + 0];
        pp[(size_t)(bg * 4 + 1) * H] = a1 * rinv[bg * 4 + 1];
        pp[(size_t)(bg * 4 + 2) * H] = a2 * rinv[bg * 4 + 2];
        pp[(size_t)(bg * 4 + 3) * H] = a3 * rinv[bg * 4 + 3];
    }
}

// ===== P4: wo_part = (bv + sum_24 ctx_part) @ wo  (288 vblocks) =============
__device__ void phase4(const MegaParams& p, float* smem, int bx, int tid) {
    for (int vb = bx; vb < 288; vb += GRID) {
        const int jt = vb % 12, sp = vb / 12, i0 = sp * 32;
        __syncthreads();
        float* Asl = smem;
        for (int e = tid; e < 512; e += BLK) {
            const int b = e >> 5, ii = e & 31;
            float v = p.bv[i0 + ii];
#pragma unroll
            for (int s2 = 0; s2 < 24; ++s2)
                v += p.ctx_part[((size_t)s2 * B + b) * H + i0 + ii];
            Asl[e] = v;
        }
        __syncthreads();
        const int jl = tid & 63, bg = tid >> 6, j = jt * 64 + jl;
        const float* wp_ = p.wo + (size_t)i0 * H + j;
        float a0 = 0, a1 = 0, a2 = 0, a3 = 0;
#pragma unroll
        for (int ii = 0; ii < 32; ++ii) {
            const float w = wp_[(size_t)ii * H];
            a0 += w * Asl[(bg * 4 + 0) * 32 + ii];
            a1 += w * Asl[(bg * 4 + 1) * 32 + ii];
            a2 += w * Asl[(bg * 4 + 2) * 32 + ii];
            a3 += w * Asl[(bg * 4 + 3) * 32 + ii];
        }
        float* pp = p.wo_part + ((size_t)sp * B) * H + j;
        pp[(size_t)(bg * 4 + 0) * H] = a0;
        pp[(size_t)(bg * 4 + 1) * H] = a1;
        pp[(size_t)(bg * 4 + 2) * H] = a2;
        pp[(size_t)(bg * 4 + 3) * H] = a3;
    }
}

// ===== P5: attn_out = LN1(sum wo_part + bo + x[:,0,:])  (16 blocks) =========
__device__ void phase5(const MegaParams& p, float* smem, int bx, int tid) {
    if (bx < B) {
        const int b = bx;
        float v[3];
#pragma unroll
        for (int c = 0; c < 3; ++c) {
            const int j = tid + 256 * c;
            float t = p.bo[j] + p.x[(size_t)b * S * H + j];
#pragma unroll
            for (int sp = 0; sp < 24; ++sp) t += p.wo_part[((size_t)sp * B + b) * H + j];
            v[c] = t;
        }
        const float mu = blockReduce256(v[0] + v[1] + v[2], smem) * (1.0f / H);
        const float d0 = v[0] - mu, d1 = v[1] - mu, d2 = v[2] - mu;
        const float var = blockReduce256(d0 * d0 + d1 * d1 + d2 * d2, smem) * (1.0f / H);
        const float rs = rsqrtf(var + EPS);
#pragma unroll
        for (int c = 0; c < 3; ++c) {
            const int j = tid + 256 * c;
            p.attn_out[(size_t)b * H + j] = (v[c] - mu) * rs * p.ln1g[j] + p.ln1b[j];
        }
    }
}

// ===== P6: ffn1_part = attn_out @ w1  (1152 vblocks) ========================
__device__ void phase6(const MegaParams& p, float* smem, int bx, int tid) {
    for (int vb = bx; vb < 1152; vb += GRID) {
        const int jt = vb % 48, sp = vb / 48, i0 = sp * 32;
        __syncthreads();
        float* Asl = smem;
        for (int e = tid; e < 512; e += BLK) {
            const int b = e >> 5, ii = e & 31;
            Asl[e] = p.attn_out[(size_t)b * H + i0 + ii];
        }
        __syncthreads();
        const int jl = tid & 63, bg = tid >> 6, j = jt * 64 + jl;
        const float* wp_ = p.w1 + (size_t)i0 * FF + j;
        float a0 = 0, a1 = 0, a2 = 0, a3 = 0;
#pragma unroll
        for (int ii = 0; ii < 32; ++ii) {
            const float w = wp_[(size_t)ii * FF];
            a0 += w * Asl[(bg * 4 + 0) * 32 + ii];
            a1 += w * Asl[(bg * 4 + 1) * 32 + ii];
            a2 += w * Asl[(bg * 4 + 2) * 32 + ii];
            a3 += w * Asl[(bg * 4 + 3) * 32 + ii];
        }
        float* pp = p.ffn1_part + ((size_t)sp * B) * FF + j;
        pp[(size_t)(bg * 4 + 0) * FF] = a0;
        pp[(size_t)(bg * 4 + 1) * FF] = a1;
        pp[(size_t)(bg * 4 + 2) * FF] = a2;
        pp[(size_t)(bg * 4 + 3) * FF] = a3;
    }
}

// ===== P7: ffn2_part = gelu(b1 + sum ffn1_part) @ w2  (576 vblocks) =========
__device__ void phase7(const MegaParams& p, float* smem, int bx, int tid) {
    for (int vb = bx; vb < 576; vb += GRID) {
        const int jt = vb % 12, sp = vb / 12, i0 = sp * 64;
        __syncthreads();
        float* Asl = smem;
        for (int e = tid; e < 1024; e += BLK) {
            const int b = e >> 6, ii = e & 63;
            float v = p.b1[i0 + ii];
#pragma unroll
            for (int s2 = 0; s2 < 24; ++s2)
                v += p.ffn1_part[((size_t)s2 * B + b) * FF + i0 + ii];
            Asl[e] = 0.5f * v * (1.0f + erff(v * 0.70710678118654752440f));
        }
        __syncthreads();
        const int jl = tid & 63, bg = tid >> 6, j = jt * 64 + jl;
        const float* wp_ = p.w2 + (size_t)i0 * H + j;
        float a0 = 0, a1 = 0, a2 = 0, a3 = 0;
#pragma unroll
        for (int ii = 0; ii < 64; ++ii) {
            const float w = wp_[(size_t)ii * H];
            a0 += w * Asl[(bg * 4 + 0) * 64 + ii];
            a1 += w * Asl[(bg * 4 + 1) * 64 + ii];
            a2 += w * Asl[(bg * 4 + 2) * 64 + ii];
            a3 += w * Asl[(bg * 4 + 3) * 64 + ii];
        }
        float* pp = p.ffn2_part + ((size_t)sp * B) * H + j;
        pp[(size_t)(bg * 4 + 0) * H] = a0;
        pp[(size_t)(bg * 4 + 1) * H] = a1;
        pp[(size_t)(bg * 4 + 2) * H] = a2;
        pp[(size_t)(bg * 4 + 3) * H] = a3;
    }
}

// ===== P8: hidden = LN2(sum ffn2_part + b2 + attn_out)  (16 blocks) =========
__device__ void phase8(const MegaParams& p, float* smem, int bx, int tid) {
    if (bx < B) {
        const int b = bx;
        float v[3];
#pragma unroll
        for (int c = 0; c < 3; ++c) {
            const int j = tid + 256 * c;
            float t = p.b2[j] + p.attn_out[(size_t)b * H + j];
#pragma unroll
            for (int sp = 0; sp < 48; ++sp) t += p.ffn2_part[((size_t)sp * B + b) * H + j];
            v[c] = t;
        }
        const float mu = blockReduce256(v[0] + v[1] + v[2], smem) * (1.0f / H);
        const float d0 = v[0] - mu, d1 = v[1] - mu, d2 = v[2] - mu;
        const float var = blockReduce256(d0 * d0 + d1 * d1 + d2 * d2, smem) * (1.0f / H);
        const float rs = rsqrtf(var + EPS);
#pragma unroll
        for (int c = 0; c < 3; ++c) {
            const int j = tid + 256 * c;
            p.hidden[(size_t)b * H + j] = (v[c] - mu) * rs * p.ln2g[j] + p.ln2b[j];
        }
    }
}

// ===== P9: pool_part = hidden @ wp  (288 vblocks) ===========================
__device__ void phase9(const MegaParams& p, float* smem, int bx, int tid) {
    for (int vb = bx; vb < 288; vb += GRID) {
        const int jt = vb % 12, sp = vb / 12, i0 = sp * 32;
        __syncthreads();
        float* Asl = smem;
        for (int e = tid; e < 512; e += BLK) {
            const int b = e >> 5, ii = e & 31;
            Asl[e] = p.hidden[(size_t)b * H + i0 + ii];
        }
        __syncthreads();
        const int jl = tid & 63, bg = tid >> 6, j = jt * 64 + jl;
        const float* wp_ = p.wp + (size_t)i0 * H + j;
        float a0 = 0, a1 = 0, a2 = 0, a3 = 0;
#pragma unroll
        for (int ii = 0; ii < 32; ++ii) {
            const float w = wp_[(size_t)ii * H];
            a0 += w * Asl[(bg * 4 + 0) * 32 + ii];
            a1 += w * Asl[(bg * 4 + 1) * 32 + ii];
            a2 += w * Asl[(bg * 4 + 2) * 32 + ii];
            a3 += w * Asl[(bg * 4 + 3) * 32 + ii];
        }
        float* pp = p.pool_part + ((size_t)sp * B) * H + j;
        pp[(size_t)(bg * 4 + 0) * H] = a0;
        pp[(size_t)(bg * 4 + 1) * H] = a1;
        pp[(size_t)(bg * 4 + 2) * H] = a2;
        pp[(size_t)(bg * 4 + 3) * H] = a3;
    }
}

// ===== P10: cls[b] = tanh(sum pool_part + bp) . wm + bm  (16 blocks) ========
__device__ void phase10(const MegaParams& p, float* smem, int bx, int tid) {
    if (bx < B) {
        const int b = bx;
        float s = 0.f;
#pragma unroll
        for (int c = 0; c < 3; ++c) {
            const int j = tid + 256 * c;
            float t = p.bp[j];
#pragma unroll
            for (int sp = 0; sp < 24; ++sp) t += p.pool_part[((size_t)sp * B + b) * H + j];
            s += tanhf(t) * p.wm[j];
        }
        s = blockReduce256(s, smem);
        if (tid == 0) p.out[b] = s + p.bm[0];
    }
}

__global__ __launch_bounds__(BLK, 1) void mega_all(MegaParams p) {
    cg::grid_group gg = cg::this_grid();
    __shared__ float smem[9664];
    const int tid = threadIdx.x, bx = blockIdx.x;
    phase0(p, smem, bx, tid);  gg.sync();
    phase1(p, smem, bx, tid);  gg.sync();
    phase2(p, smem, bx, tid);  gg.sync();
    phase3(p, smem, bx, tid);  gg.sync();
    phase4(p, smem, bx, tid);  gg.sync();
    phase5(p, smem, bx, tid);  gg.sync();
    phase6(p, smem, bx, tid);  gg.sync();
    phase7(p, smem, bx, tid);  gg.sync();
    phase8(p, smem, bx, tid);  gg.sync();
    phase9(p, smem, bx, tid);  gg.sync();
    phase10(p, smem, bx, tid);
}

__global__ __launch_bounds__(BLK, 1) void mega_one(MegaParams p, int phase) {
    __shared__ float smem[9664];
    const int tid = threadIdx.x, bx = blockIdx.x;
    switch (phase) {
        case 0:  phase0(p, smem, bx, tid);  break;
        case 1:  phase1(p, smem, bx, tid);  break;
        case 2:  phase2(p, smem, bx, tid);  break;
        case 3:  phase3(p, smem, bx, tid);  break;
        case 4:  phase4(p, smem, bx, tid);  break;
        case 5:  phase5(p, smem, bx, tid);  break;
        case 6:  phase6(p, smem, bx, tid);  break;
        case 7:  phase7(p, smem, bx, tid);  break;
        case 8:  phase8(p, smem, bx, tid);  break;
        case 9:  phase9(p, smem, bx, tid);  break;
        default: phase10(p, smem, bx, tid); break;
    }
}

} // namespace

extern "C" void kernel_launch(void* const* d_in, const int* in_sizes, int n_in,
                              void* d_out, int out_size, void* d_ws, size_t ws_size,
                              hipStream_t stream) {
    MegaParams prm;
    prm.x    = (const float*)d_in[0];
    prm.mask = (const float*)d_in[1];
    prm.wq   = (const float*)d_in[2];
    prm.bq   = (const float*)d_in[3];
    prm.wk   = (const float*)d_in[4];
    prm.bk   = (const float*)d_in[5];
    prm.wv   = (const float*)d_in[6];
    prm.bv   = (const float*)d_in[7];
    prm.wo   = (const float*)d_in[8];
    prm.bo   = (const float*)d_in[9];
    prm.ln1g = (const float*)d_in[10];
    prm.ln1b = (const float*)d_in[11];
    prm.w1   = (const float*)d_in[12];
    prm.b1   = (const float*)d_in[13];
    prm.w2   = (const float*)d_in[14];
    prm.b2   = (const float*)d_in[15];
    prm.ln2g = (const float*)d_in[16];
    prm.ln2b = (const float*)d_in[17];
    prm.wp   = (const float*)d_in[18];
    prm.bp   = (const float*)d_in[19];
    prm.wm   = (const float*)d_in[20];
    prm.bm   = (const float*)d_in[21];
    prm.out  = (float*)d_out;

    // -------- workspace: fixed block + lifetime-overlapped arena (12.5 MB) ---
    float* ws = (float*)d_ws;
    size_t o = 0;
    prm.u        = ws + o; o += (size_t)B * NH * H;       // 147456
    prm.constk   = ws + o; o += 256;
    prm.psum     = ws + o; o += (size_t)B * 32 * NH;      // 6144
    prm.attn_out = ws + o; o += (size_t)B * H;            // 12288
    prm.hidden   = ws + o; o += (size_t)B * H;            // 12288
    float* arena = ws + o;                                 // 2949120 floats
    prm.q0_part   = arena;                                 // P0-P1 (dies before P2)
    prm.xpart     = arena;                                 // P2-P3: 16*B*NH*H = 2359296
    prm.ctx_part  = arena + (size_t)16 * B * NH * H;       // P3-P4: 294912
    prm.wo_part   = arena + (size_t)16 * B * NH * H + 24 * B * H;  // P4-P5
    prm.ffn1_part = arena;                                 // P6-P7: 1179648 (xpart dead)
    prm.ffn2_part = arena + (size_t)24 * B * FF;           // P7-P8: 589824
    prm.pool_part = arena;                                 // P9-P10
    (void)ws_size; (void)in_sizes; (void)n_in; (void)out_size;

    void* args[] = { &prm };
    hipError_t err = hipLaunchCooperativeKernel((const void*)mega_all,
                                                dim3(GRID), dim3(BLK),
                                                args, 0, stream);
    if (err != hipSuccess) {
        // fallback: identical phases as 11 plain launches (kernel boundaries
        // provide the grid-wide ordering instead of gg.sync)
        (void)hipGetLastError();
        for (int ph = 0; ph <= 10; ++ph)
            hipLaunchKernelGGL(mega_one, dim3(GRID), dim3(BLK), 0, stream, prm, ph);
    }
}

// Round 6
// 255.656 us; speedup vs baseline: 2.1180x; 2.1180x over previous
//
#include <hip/hip_runtime.h>
#include <math.h>

namespace {

constexpr int B  = 16;
constexpr int S  = 1024;
constexpr int H  = 768;
constexpr int NH = 12;
constexpr int DH = 64;
constexpr int FF = 3072;
constexpr float EPS = 1e-12f;

__device__ __forceinline__ float waveReduceSum(float v) {
#pragma unroll
    for (int d = 1; d < 64; d <<= 1) v += __shfl_xor(v, d);
    return v;
}

__device__ __forceinline__ float blockReduceSum768(float v, float* red) {
    const int lane = threadIdx.x & 63;
    const int wid  = threadIdx.x >> 6;
    v = waveReduceSum(v);
    __syncthreads();
    if (lane == 0) red[wid] = v;
    __syncthreads();
    float s = 0.f;
#pragma unroll
    for (int w = 0; w < 12; ++w) s += red[w];
    return s;
}

// ---------------------------------------------------------------------------
// split-K partial GEMM over the 16 CLS rows (R3-proven):
//   part[sp][b][j] = sum_{i in split sp} A[b,i] * W[i,j]
// ---------------------------------------------------------------------------
template <int K, int ISPL, int N>
__global__ __launch_bounds__(256) void gemm_partial(
        const float* __restrict__ A, int lda,
        const float* __restrict__ W, float* __restrict__ part) {
    constexpr int IR = K / ISPL;
    __shared__ float Asl[B * IR];
    const int jt  = blockIdx.x;
    const int sp  = blockIdx.y;
    const int i0  = sp * IR;
    const int tid = threadIdx.x;

    for (int e = tid; e < B * IR; e += 256) {
        const int b = e / IR, ii = e % IR;
        Asl[e] = A[(size_t)b * lda + i0 + ii];
    }
    __syncthreads();

    const int jl = tid & 63;
    const int bg = tid >> 6;
    const int j  = jt * 64 + jl;
    const float* wp_ = W + (size_t)i0 * N + j;
    float acc0 = 0.f, acc1 = 0.f, acc2 = 0.f, acc3 = 0.f;
#pragma unroll
    for (int ii = 0; ii < IR; ++ii) {
        const float w = wp_[(size_t)ii * N];
        acc0 += w * Asl[(bg * 4 + 0) * IR + ii];
        acc1 += w * Asl[(bg * 4 + 1) * IR + ii];
        acc2 += w * Asl[(bg * 4 + 2) * IR + ii];
        acc3 += w * Asl[(bg * 4 + 3) * IR + ii];
    }
    float* pp = part + ((size_t)sp * B) * N + j;
    pp[(size_t)(bg * 4 + 0) * N] = acc0;
    pp[(size_t)(bg * 4 + 1) * N] = acc1;
    pp[(size_t)(bg * 4 + 2) * N] = acc2;
    pp[(size_t)(bg * 4 + 3) * N] = acc3;
}

// A[b,i] = bias[i] + sum_sp2 Ain[sp2][b][i]
template <int K, int ISPL, int N, int RED>
__global__ __launch_bounds__(256) void gemm_partial_red(
        const float* __restrict__ Ain, const float* __restrict__ bias,
        const float* __restrict__ W, float* __restrict__ part) {
    constexpr int IR = K / ISPL;
    __shared__ float Asl[B * IR];
    const int jt  = blockIdx.x;
    const int sp  = blockIdx.y;
    const int i0  = sp * IR;
    const int tid = threadIdx.x;

    for (int e = tid; e < B * IR; e += 256) {
        const int b = e / IR, ii = e % IR;
        float v = bias[i0 + ii];
#pragma unroll
        for (int sp2 = 0; sp2 < RED; ++sp2)
            v += Ain[((size_t)sp2 * B + b) * K + i0 + ii];
        Asl[e] = v;
    }
    __syncthreads();

    const int jl = tid & 63;
    const int bg = tid >> 6;
    const int j  = jt * 64 + jl;
    const float* wp_ = W + (size_t)i0 * N + j;
    float acc0 = 0.f, acc1 = 0.f, acc2 = 0.f, acc3 = 0.f;
#pragma unroll
    for (int ii = 0; ii < IR; ++ii) {
        const float w = wp_[(size_t)ii * N];
        acc0 += w * Asl[(bg * 4 + 0) * IR + ii];
        acc1 += w * Asl[(bg * 4 + 1) * IR + ii];
        acc2 += w * Asl[(bg * 4 + 2) * IR + ii];
        acc3 += w * Asl[(bg * 4 + 3) * IR + ii];
    }
    float* pp = part + ((size_t)sp * B) * N + j;
    pp[(size_t)(bg * 4 + 0) * N] = acc0;
    pp[(size_t)(bg * 4 + 1) * N] = acc1;
    pp[(size_t)(bg * 4 + 2) * N] = acc2;
    pp[(size_t)(bg * 4 + 3) * N] = acc3;
}

// Same but staging applies exact GELU
template <int K, int ISPL, int N, int RED>
__global__ __launch_bounds__(256) void gemm_partial_red_gelu(
        const float* __restrict__ Ain, const float* __restrict__ bias,
        const float* __restrict__ W, float* __restrict__ part) {
    constexpr int IR = K / ISPL;
    __shared__ float Asl[B * IR];
    const int jt  = blockIdx.x;
    const int sp  = blockIdx.y;
    const int i0  = sp * IR;
    const int tid = threadIdx.x;

    for (int e = tid; e < B * IR; e += 256) {
        const int b = e / IR, ii = e % IR;
        float v = bias[i0 + ii];
#pragma unroll
        for (int sp2 = 0; sp2 < RED; ++sp2)
            v += Ain[((size_t)sp2 * B + b) * K + i0 + ii];
        Asl[e] = 0.5f * v * (1.0f + erff(v * 0.70710678118654752440f));
    }
    __syncthreads();

    const int jl = tid & 63;
    const int bg = tid >> 6;
    const int j  = jt * 64 + jl;
    const float* wp_ = W + (size_t)i0 * N + j;
    float acc0 = 0.f, acc1 = 0.f, acc2 = 0.f, acc3 = 0.f;
#pragma unroll 32
    for (int ii = 0; ii < IR; ++ii) {
        const float w = wp_[(size_t)ii * N];
        acc0 += w * Asl[(bg * 4 + 0) * IR + ii];
        acc1 += w * Asl[(bg * 4 + 1) * IR + ii];
        acc2 += w * Asl[(bg * 4 + 2) * IR + ii];
        acc3 += w * Asl[(bg * 4 + 3) * IR + ii];
    }
    float* pp = part + ((size_t)sp * B) * N + j;
    pp[(size_t)(bg * 4 + 0) * N] = acc0;
    pp[(size_t)(bg * 4 + 1) * N] = acc1;
    pp[(size_t)(bg * 4 + 2) * N] = acc2;
    pp[(size_t)(bg * 4 + 3) * N] = acc3;
}

// ===== fused q0 + u + constk; grid (B*NH), block 256 ========================
// q0h[d] = bq + x[b,0,:] . wq[:, h*64+d];  u[b,h,i] = wk[i,head] . q0h;
// constk[b,h] = bk_head . q0h
__global__ __launch_bounds__(256) void qu_kernel(
        const float* __restrict__ x, const float* __restrict__ wq,
        const float* __restrict__ bq, const float* __restrict__ wk,
        const float* __restrict__ bk, float* __restrict__ u,
        float* __restrict__ constk) {
    const int b = blockIdx.x / NH, h = blockIdx.x % NH;
    __shared__ float xs[H];
    __shared__ float qp[4][DH];
    __shared__ __align__(16) float qh[DH];
    const int tid = threadIdx.x;
    for (int e = tid; e < H; e += 256) xs[e] = x[(size_t)b * S * H + e];
    __syncthreads();
    {
        const int d = tid & 63, pr = tid >> 6;   // 4 partials of 192 i's
        float qacc = 0.f;
        const float* wqc = wq + (size_t)(pr * 192) * H + h * DH + d;
        const float* xsp = xs + pr * 192;
#pragma unroll 8
        for (int i = 0; i < 192; ++i) qacc += wqc[(size_t)i * H] * xsp[i];
        qp[pr][d] = qacc;
    }
    __syncthreads();
    if (tid < DH)
        qh[tid] = bq[h * DH + tid] + qp[0][tid] + qp[1][tid] + qp[2][tid] + qp[3][tid];
    __syncthreads();
    if (tid < DH) {   // wave 0 exactly
        float v = bk[h * DH + tid] * qh[tid];
        v = waveReduceSum(v);
        if (tid == 0) constk[b * NH + h] = v;
    }
    const int jj = tid & 3, iq = tid >> 2;
    const float4* qv = (const float4*)qh;
    float4 q4[4];
#pragma unroll
    for (int c = 0; c < 4; ++c) q4[c] = qv[jj * 4 + c];
#pragma unroll 4
    for (int ir = 0; ir < 12; ++ir) {
        const int i = ir * 64 + iq;
        const float4* wr = (const float4*)(wk + (size_t)i * H + h * DH);
        float s = 0.f;
#pragma unroll
        for (int c = 0; c < 4; ++c) {
            const float4 w = wr[jj * 4 + c];
            s += w.x * q4[c].x + w.y * q4[c].y + w.z * q4[c].z + w.w * q4[c].w;
        }
        s += __shfl_xor(s, 1);
        s += __shfl_xor(s, 2);
        if (jj == 0) u[((size_t)(b * NH + h)) * H + i] = s;
    }
}

// ===== fused score(exp) + psum + unnormalized xbar partial ==================
// grid (B, 32), block 256; writes psum[b][kt][h], xpart[(b*32+kt)][h][:]
__global__ __launch_bounds__(256, 2) void score_xbar(
        const float* __restrict__ x, const float* __restrict__ u,
        const float* __restrict__ constk, const float* __restrict__ mask,
        float* __restrict__ psum, float* __restrict__ xpart) {
    const int b  = blockIdx.x;
    const int kt = blockIdx.y;
    __shared__ __align__(16) float ul[NH * H];   // 9216
    __shared__ float e_sh[32 * NH];              // 384
    __shared__ float ck[NH];
    __shared__ float wsum[4][NH];
    const int tid = threadIdx.x;
    {
        const float4* ug = (const float4*)(u + (size_t)b * NH * H);
        float4* ul4 = (float4*)ul;
        for (int e = tid; e < NH * H / 4; e += 256) ul4[e] = ug[e];
        if (tid < NH) ck[tid] = constk[b * NH + tid];
    }
    __syncthreads();
    const int jj = tid & 15, kk = tid >> 4;
    const int k0 = kt * 32 + kk * 2;
    float4 xv0[12], xv1[12];
    {
        const float4* xr0 = (const float4*)(x + ((size_t)b * S + k0) * H);
        const float4* xr1 = (const float4*)(x + ((size_t)b * S + k0 + 1) * H);
#pragma unroll
        for (int t = 0; t < 12; ++t) { xv0[t] = xr0[jj + 16 * t]; xv1[t] = xr1[jj + 16 * t]; }
    }
    const float4* ul4 = (const float4*)ul;
    float acc0[NH], acc1[NH];
#pragma unroll
    for (int h = 0; h < NH; ++h) {
        float a0 = 0.f, a1 = 0.f;
#pragma unroll
        for (int t = 0; t < 12; ++t) {
            const float4 uv = ul4[h * 192 + jj + 16 * t];
            a0 += xv0[t].x * uv.x + xv0[t].y * uv.y + xv0[t].z * uv.z + xv0[t].w * uv.w;
            a1 += xv1[t].x * uv.x + xv1[t].y * uv.y + xv1[t].z * uv.z + xv1[t].w * uv.w;
        }
        acc0[h] = a0; acc1[h] = a1;
    }
#pragma unroll
    for (int h = 0; h < NH; ++h) {
#pragma unroll
        for (int d = 1; d < 16; d <<= 1) {
            acc0[h] += __shfl_xor(acc0[h], d);
            acc1[h] += __shfl_xor(acc1[h], d);
        }
    }
    const float mk0 = mask[b * S + k0];
    const float mk1 = mask[b * S + k0 + 1];
    float e0[NH], e1[NH], ps[NH];
#pragma unroll
    for (int h = 0; h < NH; ++h) {
        e0[h] = expf(acc0[h] * 0.125f + ck[h] + mk0);
        e1[h] = expf(acc1[h] * 0.125f + ck[h] + mk1);
        ps[h] = e0[h] + e1[h];
    }
    if (jj == 0) {
#pragma unroll
        for (int h = 0; h < NH; ++h) {
            e_sh[(kk * 2) * NH + h]     = e0[h];
            e_sh[(kk * 2 + 1) * NH + h] = e1[h];
        }
    }
#pragma unroll
    for (int h = 0; h < NH; ++h) {
        ps[h] += __shfl_xor(ps[h], 16);
        ps[h] += __shfl_xor(ps[h], 32);
    }
    const int wid = tid >> 6;
    if ((tid & 63) == 0) {
#pragma unroll
        for (int h = 0; h < NH; ++h) wsum[wid][h] = ps[h];
    }
    __syncthreads();
    if (tid < NH)
        psum[((size_t)(b * 32 + kt)) * NH + tid] =
            wsum[0][tid] + wsum[1][tid] + wsum[2][tid] + wsum[3][tid];

    // phase B: unnormalized xbar partial; x rows are cache-hot from phase A
    float aB0[NH], aB1[NH], aB2[NH];
#pragma unroll
    for (int h = 0; h < NH; ++h) { aB0[h] = 0.f; aB1[h] = 0.f; aB2[h] = 0.f; }
    const float* xr = x + ((size_t)b * S + kt * 32) * H;
#pragma unroll 2
    for (int k = 0; k < 32; ++k) {
        const float x0 = xr[(size_t)k * H + tid];
        const float x1 = xr[(size_t)k * H + tid + 256];
        const float x2 = xr[(size_t)k * H + tid + 512];
#pragma unroll
        for (int h = 0; h < NH; ++h) {
            const float ev = e_sh[k * NH + h];
            aB0[h] += ev * x0; aB1[h] += ev * x1; aB2[h] += ev * x2;
        }
    }
    float* op = xpart + ((size_t)(b * 32 + kt)) * NH * H;
#pragma unroll
    for (int h = 0; h < NH; ++h) {
        op[(size_t)h * H + tid]       = aB0[h];
        op[(size_t)h * H + tid + 256] = aB1[h];
        op[(size_t)h * H + tid + 512] = aB2[h];
    }
}

// ===== ctx_part[sp][b][head*64+jl] = ((sum_32 xpart)*rinv) @ wv_head ========
template <int ISPL>
__global__ __launch_bounds__(256) void gemm_xpart(
        const float* __restrict__ xpart, const float* __restrict__ psum,
        const float* __restrict__ W, float* __restrict__ part) {
    constexpr int IR = H / ISPL;
    __shared__ float Asl[B * IR];
    __shared__ float rinv[B];
    const int jt  = blockIdx.x;       // head
    const int sp  = blockIdx.y;
    const int i0  = sp * IR;
    const int tid = threadIdx.x;

    if (tid < B) {
        float s = 0.f;
#pragma unroll
        for (int kt = 0; kt < 32; ++kt)
            s += psum[((size_t)(tid * 32 + kt)) * NH + jt];
        rinv[tid] = 1.0f / s;
    }
    for (int e = tid; e < B * IR; e += 256) {
        const int b = e / IR, ii = e % IR;
        float v = 0.f;
#pragma unroll
        for (int s2 = 0; s2 < 32; ++s2)
            v += xpart[((size_t)(b * 32 + s2)) * NH * H + (size_t)jt * H + i0 + ii];
        Asl[e] = v;
    }
    __syncthreads();

    const int jl = tid & 63, bg = tid >> 6;
    const int j = jt * 64 + jl;
    const float* wp_ = W + (size_t)i0 * H + j;
    float a0 = 0, a1 = 0, a2 = 0, a3 = 0;
#pragma unroll
    for (int ii = 0; ii < IR; ++ii) {
        const float w = wp_[(size_t)ii * H];
        a0 += w * Asl[(bg * 4 + 0) * IR + ii];
        a1 += w * Asl[(bg * 4 + 1) * IR + ii];
        a2 += w * Asl[(bg * 4 + 2) * IR + ii];
        a3 += w * Asl[(bg * 4 + 3) * IR + ii];
    }
    float* pp = part + ((size_t)sp * B) * H + j;
    pp[(size_t)(bg * 4 + 0) * H] = a0 * rinv[bg * 4 + 0];
    pp[(size_t)(bg * 4 + 1) * H] = a1 * rinv[bg * 4 + 1];
    pp[(size_t)(bg * 4 + 2) * H] = a2 * rinv[bg * 4 + 2];
    pp[(size_t)(bg * 4 + 3) * H] = a3 * rinv[bg * 4 + 3];
}

// ===== LN over sum of partials + bias + residual ============================
template <int ISPL>
__global__ __launch_bounds__(768) void ln_kernel(
        const float* __restrict__ part, const float* __restrict__ bias,
        const float* __restrict__ resid, int residStride,
        const float* __restrict__ g, const float* __restrict__ bet,
        float* __restrict__ out) {
    __shared__ float red[12];
    const int b = blockIdx.x, j = threadIdx.x;
    float v = bias[j] + resid[(size_t)b * residStride + j];
#pragma unroll
    for (int sp = 0; sp < ISPL; ++sp) v += part[((size_t)sp * B + b) * H + j];
    const float mu = blockReduceSum768(v, red) * (1.0f / H);
    const float d  = v - mu;
    const float var = blockReduceSum768(d * d, red) * (1.0f / H);
    out[(size_t)b * H + j] = d * rsqrtf(var + EPS) * g[j] + bet[j];
}

// ===== fused pooler + classifier: grid B, block 768 =========================
// pooled[j] = tanh(hidden[b,:] . wp[:,j] + bp[j]); out[b] = pooled . wm + bm
__global__ __launch_bounds__(768) void poolcls_kernel(
        const float* __restrict__ hidden, const float* __restrict__ wp,
        const float* __restrict__ bp, const float* __restrict__ wm,
        const float* __restrict__ bm, float* __restrict__ out) {
    __shared__ float hs[H];
    __shared__ float red[12];
    const int b = blockIdx.x, j = threadIdx.x;
    hs[j] = hidden[(size_t)b * H + j];
    __syncthreads();
    float acc = bp[j];
    const float* wpc = wp + j;
#pragma unroll 8
    for (int i = 0; i < H; ++i) acc += wpc[(size_t)i * H] * hs[i];
    const float s = blockReduceSum768(tanhf(acc) * wm[j], red);
    if (j == 0) out[b] = s + bm[0];
}

} // namespace

extern "C" void kernel_launch(void* const* d_in, const int* in_sizes, int n_in,
                              void* d_out, int out_size, void* d_ws, size_t ws_size,
                              hipStream_t stream) {
    const float* x    = (const float*)d_in[0];
    const float* mask = (const float*)d_in[1];
    const float* wq   = (const float*)d_in[2];
    const float* bq   = (const float*)d_in[3];
    const float* wk   = (const float*)d_in[4];
    const float* bk   = (const float*)d_in[5];
    const float* wv   = (const float*)d_in[6];
    const float* bv   = (const float*)d_in[7];
    const float* wo   = (const float*)d_in[8];
    const float* bo   = (const float*)d_in[9];
    const float* ln1g = (const float*)d_in[10];
    const float* ln1b = (const float*)d_in[11];
    const float* w1   = (const float*)d_in[12];
    const float* b1   = (const float*)d_in[13];
    const float* w2   = (const float*)d_in[14];
    const float* b2   = (const float*)d_in[15];
    const float* ln2g = (const float*)d_in[16];
    const float* ln2b = (const float*)d_in[17];
    const float* wp   = (const float*)d_in[18];
    const float* bp   = (const float*)d_in[19];
    const float* wm   = (const float*)d_in[20];
    const float* bm   = (const float*)d_in[21];
    float* out = (float*)d_out;

    // -------- workspace, linear layout (~30 MB of the 256 MiB d_ws) ---------
    float* ws = (float*)d_ws;
    size_t o = 0;
    float* u         = ws + o; o += (size_t)B * NH * H;       // 147456
    float* constk    = ws + o; o += 256;
    float* psum      = ws + o; o += (size_t)B * 32 * NH;      // 6144
    float* attn_out  = ws + o; o += (size_t)B * H;
    float* hidden    = ws + o; o += (size_t)B * H;
    float* xpart     = ws + o; o += (size_t)32 * B * NH * H;  // 4718592
    float* ctx_part  = ws + o; o += (size_t)24 * B * H;
    float* wo_part   = ws + o; o += (size_t)24 * B * H;
    float* ffn1_part = ws + o; o += (size_t)24 * B * FF;      // 1179648
    float* ffn2_part = ws + o; o += (size_t)48 * B * H;       // 589824
    (void)ws_size; (void)in_sizes; (void)n_in; (void)out_size;

    // 1) q0 + u + constk (fused)
    qu_kernel<<<B * NH, 256, 0, stream>>>(x, wq, bq, wk, bk, u, constk);

    // 2) scores->exp + row-sum partials + unnormalized xbar partials (fused)
    score_xbar<<<dim3(B, 32), 256, 0, stream>>>(x, u, constk, mask, psum, xpart);

    // 3) ctx partials: normalized xbar per-head slice @ wv
    gemm_xpart<24><<<dim3(12, 24), 256, 0, stream>>>(xpart, psum, wv, ctx_part);

    // 4) wo GEMM (fused ctx reduce + bv)
    gemm_partial_red<H, 24, H, 24><<<dim3(12, 24), 256, 0, stream>>>(ctx_part, bv, wo, wo_part);

    // 5) LN1 with residual x[:,0,:]
    ln_kernel<24><<<B, 768, 0, stream>>>(wo_part, bo, x, S * H, ln1g, ln1b, attn_out);

    // 6) FFN1
    gemm_partial<H, 24, FF><<<dim3(48, 24), 256, 0, stream>>>(attn_out, H, w1, ffn1_part);

    // 7) FFN2 (gelu fused into staging)
    gemm_partial_red_gelu<FF, 48, H, 24><<<dim3(12, 48), 256, 0, stream>>>(ffn1_part, b1, w2, ffn2_part);

    // 8) LN2 with residual attn_out
    ln_kernel<48><<<B, 768, 0, stream>>>(ffn2_part, b2, attn_out, H, ln2g, ln2b, hidden);

    // 9) pooler + classifier (fused)
    poolcls_kernel<<<B, 768, 0, stream>>>(hidden, wp, bp, wm, bm, out);
}

// Round 7
// 211.115 us; speedup vs baseline: 2.5648x; 1.2110x over previous
//
#include <hip/hip_runtime.h>
#include <math.h>

namespace {

constexpr int B  = 16;
constexpr int S  = 1024;
constexpr int H  = 768;
constexpr int NH = 12;
constexpr int DH = 64;
constexpr int FF = 3072;
constexpr float EPS = 1e-12f;

__device__ __forceinline__ float waveReduceSum(float v) {
#pragma unroll
    for (int d = 1; d < 64; d <<= 1) v += __shfl_xor(v, d);
    return v;
}

__device__ __forceinline__ float blockReduceSum768(float v, float* red) {
    const int lane = threadIdx.x & 63;
    const int wid  = threadIdx.x >> 6;
    v = waveReduceSum(v);
    __syncthreads();
    if (lane == 0) red[wid] = v;
    __syncthreads();
    float s = 0.f;
#pragma unroll
    for (int w = 0; w < 12; ++w) s += red[w];
    return s;
}

// ---------------------------------------------------------------------------
// split-K partial GEMM over the 16 CLS rows (R3-proven):
//   part[sp][b][j] = sum_{i in split sp} A[b,i] * W[i,j]
// grid (N/64, ISPL), block 256 = 64 j-lanes x 4 b-groups
// ---------------------------------------------------------------------------
template <int K, int ISPL, int N>
__global__ __launch_bounds__(256) void gemm_partial(
        const float* __restrict__ A, int lda,
        const float* __restrict__ W, float* __restrict__ part) {
    constexpr int IR = K / ISPL;
    __shared__ float Asl[B * IR];
    const int jt  = blockIdx.x;
    const int sp  = blockIdx.y;
    const int i0  = sp * IR;
    const int tid = threadIdx.x;

    for (int e = tid; e < B * IR; e += 256) {
        const int b = e / IR, ii = e % IR;
        Asl[e] = A[(size_t)b * lda + i0 + ii];
    }
    __syncthreads();

    const int jl = tid & 63;
    const int bg = tid >> 6;
    const int j  = jt * 64 + jl;
    const float* wp_ = W + (size_t)i0 * N + j;
    float acc0 = 0.f, acc1 = 0.f, acc2 = 0.f, acc3 = 0.f;
#pragma unroll
    for (int ii = 0; ii < IR; ++ii) {
        const float w = wp_[(size_t)ii * N];
        acc0 += w * Asl[(bg * 4 + 0) * IR + ii];
        acc1 += w * Asl[(bg * 4 + 1) * IR + ii];
        acc2 += w * Asl[(bg * 4 + 2) * IR + ii];
        acc3 += w * Asl[(bg * 4 + 3) * IR + ii];
    }
    float* pp = part + ((size_t)sp * B) * N + j;
    pp[(size_t)(bg * 4 + 0) * N] = acc0;
    pp[(size_t)(bg * 4 + 1) * N] = acc1;
    pp[(size_t)(bg * 4 + 2) * N] = acc2;
    pp[(size_t)(bg * 4 + 3) * N] = acc3;
}

// A[b,i] = bias[i] + sum_sp2 Ain[sp2][b][i]
template <int K, int ISPL, int N, int RED>
__global__ __launch_bounds__(256) void gemm_partial_red(
        const float* __restrict__ Ain, const float* __restrict__ bias,
        const float* __restrict__ W, float* __restrict__ part) {
    constexpr int IR = K / ISPL;
    __shared__ float Asl[B * IR];
    const int jt  = blockIdx.x;
    const int sp  = blockIdx.y;
    const int i0  = sp * IR;
    const int tid = threadIdx.x;

    for (int e = tid; e < B * IR; e += 256) {
        const int b = e / IR, ii = e % IR;
        float v = bias[i0 + ii];
#pragma unroll
        for (int sp2 = 0; sp2 < RED; ++sp2)
            v += Ain[((size_t)sp2 * B + b) * K + i0 + ii];
        Asl[e] = v;
    }
    __syncthreads();

    const int jl = tid & 63;
    const int bg = tid >> 6;
    const int j  = jt * 64 + jl;
    const float* wp_ = W + (size_t)i0 * N + j;
    float acc0 = 0.f, acc1 = 0.f, acc2 = 0.f, acc3 = 0.f;
#pragma unroll
    for (int ii = 0; ii < IR; ++ii) {
        const float w = wp_[(size_t)ii * N];
        acc0 += w * Asl[(bg * 4 + 0) * IR + ii];
        acc1 += w * Asl[(bg * 4 + 1) * IR + ii];
        acc2 += w * Asl[(bg * 4 + 2) * IR + ii];
        acc3 += w * Asl[(bg * 4 + 3) * IR + ii];
    }
    float* pp = part + ((size_t)sp * B) * N + j;
    pp[(size_t)(bg * 4 + 0) * N] = acc0;
    pp[(size_t)(bg * 4 + 1) * N] = acc1;
    pp[(size_t)(bg * 4 + 2) * N] = acc2;
    pp[(size_t)(bg * 4 + 3) * N] = acc3;
}

// Same but staging applies exact GELU
template <int K, int ISPL, int N, int RED>
__global__ __launch_bounds__(256) void gemm_partial_red_gelu(
        const float* __restrict__ Ain, const float* __restrict__ bias,
        const float* __restrict__ W, float* __restrict__ part) {
    constexpr int IR = K / ISPL;
    __shared__ float Asl[B * IR];
    const int jt  = blockIdx.x;
    const int sp  = blockIdx.y;
    const int i0  = sp * IR;
    const int tid = threadIdx.x;

    for (int e = tid; e < B * IR; e += 256) {
        const int b = e / IR, ii = e % IR;
        float v = bias[i0 + ii];
#pragma unroll
        for (int sp2 = 0; sp2 < RED; ++sp2)
            v += Ain[((size_t)sp2 * B + b) * K + i0 + ii];
        Asl[e] = 0.5f * v * (1.0f + erff(v * 0.70710678118654752440f));
    }
    __syncthreads();

    const int jl = tid & 63;
    const int bg = tid >> 6;
    const int j  = jt * 64 + jl;
    const float* wp_ = W + (size_t)i0 * N + j;
    float acc0 = 0.f, acc1 = 0.f, acc2 = 0.f, acc3 = 0.f;
#pragma unroll 32
    for (int ii = 0; ii < IR; ++ii) {
        const float w = wp_[(size_t)ii * N];
        acc0 += w * Asl[(bg * 4 + 0) * IR + ii];
        acc1 += w * Asl[(bg * 4 + 1) * IR + ii];
        acc2 += w * Asl[(bg * 4 + 2) * IR + ii];
        acc3 += w * Asl[(bg * 4 + 3) * IR + ii];
    }
    float* pp = part + ((size_t)sp * B) * N + j;
    pp[(size_t)(bg * 4 + 0) * N] = acc0;
    pp[(size_t)(bg * 4 + 1) * N] = acc1;
    pp[(size_t)(bg * 4 + 2) * N] = acc2;
    pp[(size_t)(bg * 4 + 3) * N] = acc3;
}

// u[b,h,i] = sum_d wk[i, h*64+d] * (q0 reduced); constk[b,h] = bk_h . q0_h
// grid (B*NH), block 256 = 64 i x 4 jj   (R3-proven)
__global__ __launch_bounds__(256) void u_kernel(
        const float* __restrict__ q0_part, const float* __restrict__ bq,
        const float* __restrict__ wk, const float* __restrict__ bk,
        float* __restrict__ u, float* __restrict__ constk) {
    const int b = blockIdx.x / NH, h = blockIdx.x % NH;
    __shared__ __align__(16) float qh[DH];
    const int tid = threadIdx.x;
    if (tid < DH) {
        float v = bq[h * DH + tid];
#pragma unroll
        for (int sp = 0; sp < 24; ++sp)
            v += q0_part[((size_t)sp * B + b) * H + h * DH + tid];
        qh[tid] = v;
    }
    __syncthreads();
    if (tid < DH) {
        float v = bk[h * DH + tid] * qh[tid];
        v = waveReduceSum(v);
        if (tid == 0) constk[b * NH + h] = v;
    }
    const int jj = tid & 3, iq = tid >> 2;
    const float4* qv = (const float4*)qh;
    float4 q4[4];
#pragma unroll
    for (int c = 0; c < 4; ++c) q4[c] = qv[jj * 4 + c];
#pragma unroll 4
    for (int ir = 0; ir < 12; ++ir) {
        const int i = ir * 64 + iq;
        const float4* wr = (const float4*)(wk + (size_t)i * H + h * DH);
        float s = 0.f;
#pragma unroll
        for (int c = 0; c < 4; ++c) {
            const float4 w = wr[jj * 4 + c];
            s += w.x * q4[c].x + w.y * q4[c].y + w.z * q4[c].z + w.w * q4[c].w;
        }
        s += __shfl_xor(s, 1);
        s += __shfl_xor(s, 2);
        if (jj == 0) u[((size_t)(b * NH + h)) * H + i] = s;
    }
}

// ===== fused score(exp) + psum + unnormalized xbar partial ==================
// grid (B, 32), block 256; writes psum[b][kt][h], xpart[(b*32+kt)][h][:]
__global__ __launch_bounds__(256, 2) void score_xbar(
        const float* __restrict__ x, const float* __restrict__ u,
        const float* __restrict__ constk, const float* __restrict__ mask,
        float* __restrict__ psum, float* __restrict__ xpart) {
    const int b  = blockIdx.x;
    const int kt = blockIdx.y;
    __shared__ __align__(16) float ul[NH * H];   // 9216
    __shared__ float e_sh[32 * NH];              // 384
    __shared__ float ck[NH];
    __shared__ float wsum[4][NH];
    const int tid = threadIdx.x;
    {
        const float4* ug = (const float4*)(u + (size_t)b * NH * H);
        float4* ul4 = (float4*)ul;
        for (int e = tid; e < NH * H / 4; e += 256) ul4[e] = ug[e];
        if (tid < NH) ck[tid] = constk[b * NH + tid];
    }
    __syncthreads();
    const int jj = tid & 15, kk = tid >> 4;
    const int k0 = kt * 32 + kk * 2;
    float4 xv0[12], xv1[12];
    {
        const float4* xr0 = (const float4*)(x + ((size_t)b * S + k0) * H);
        const float4* xr1 = (const float4*)(x + ((size_t)b * S + k0 + 1) * H);
#pragma unroll
        for (int t = 0; t < 12; ++t) { xv0[t] = xr0[jj + 16 * t]; xv1[t] = xr1[jj + 16 * t]; }
    }
    const float4* ul4 = (const float4*)ul;
    float acc0[NH], acc1[NH];
#pragma unroll
    for (int h = 0; h < NH; ++h) {
        float a0 = 0.f, a1 = 0.f;
#pragma unroll
        for (int t = 0; t < 12; ++t) {
            const float4 uv = ul4[h * 192 + jj + 16 * t];
            a0 += xv0[t].x * uv.x + xv0[t].y * uv.y + xv0[t].z * uv.z + xv0[t].w * uv.w;
            a1 += xv1[t].x * uv.x + xv1[t].y * uv.y + xv1[t].z * uv.z + xv1[t].w * uv.w;
        }
        acc0[h] = a0; acc1[h] = a1;
    }
#pragma unroll
    for (int h = 0; h < NH; ++h) {
#pragma unroll
        for (int d = 1; d < 16; d <<= 1) {
            acc0[h] += __shfl_xor(acc0[h], d);
            acc1[h] += __shfl_xor(acc1[h], d);
        }
    }
    const float mk0 = mask[b * S + k0];
    const float mk1 = mask[b * S + k0 + 1];
    float e0[NH], e1[NH], ps[NH];
#pragma unroll
    for (int h = 0; h < NH; ++h) {
        e0[h] = expf(acc0[h] * 0.125f + ck[h] + mk0);
        e1[h] = expf(acc1[h] * 0.125f + ck[h] + mk1);
        ps[h] = e0[h] + e1[h];
    }
    if (jj == 0) {
#pragma unroll
        for (int h = 0; h < NH; ++h) {
            e_sh[(kk * 2) * NH + h]     = e0[h];
            e_sh[(kk * 2 + 1) * NH + h] = e1[h];
        }
    }
#pragma unroll
    for (int h = 0; h < NH; ++h) {
        ps[h] += __shfl_xor(ps[h], 16);
        ps[h] += __shfl_xor(ps[h], 32);
    }
    const int wid = tid >> 6;
    if ((tid & 63) == 0) {
#pragma unroll
        for (int h = 0; h < NH; ++h) wsum[wid][h] = ps[h];
    }
    __syncthreads();
    if (tid < NH)
        psum[((size_t)(b * 32 + kt)) * NH + tid] =
            wsum[0][tid] + wsum[1][tid] + wsum[2][tid] + wsum[3][tid];

    // phase B: unnormalized xbar partial; x rows are cache-hot from phase A
    float aB0[NH], aB1[NH], aB2[NH];
#pragma unroll
    for (int h = 0; h < NH; ++h) { aB0[h] = 0.f; aB1[h] = 0.f; aB2[h] = 0.f; }
    const float* xr = x + ((size_t)b * S + kt * 32) * H;
#pragma unroll 2
    for (int k = 0; k < 32; ++k) {
        const float x0 = xr[(size_t)k * H + tid];
        const float x1 = xr[(size_t)k * H + tid + 256];
        const float x2 = xr[(size_t)k * H + tid + 512];
#pragma unroll
        for (int h = 0; h < NH; ++h) {
            const float ev = e_sh[k * NH + h];
            aB0[h] += ev * x0; aB1[h] += ev * x1; aB2[h] += ev * x2;
        }
    }
    float* op = xpart + ((size_t)(b * 32 + kt)) * NH * H;
#pragma unroll
    for (int h = 0; h < NH; ++h) {
        op[(size_t)h * H + tid]       = aB0[h];
        op[(size_t)h * H + tid + 256] = aB1[h];
        op[(size_t)h * H + tid + 512] = aB2[h];
    }
}

// ===== ctx_part[sp][b][head*64+jl] = ((sum_32 xpart)*rinv) @ wv_head ========
template <int ISPL>
__global__ __launch_bounds__(256) void gemm_xpart(
        const float* __restrict__ xpart, const float* __restrict__ psum,
        const float* __restrict__ W, float* __restrict__ part) {
    constexpr int IR = H / ISPL;
    __shared__ float Asl[B * IR];
    __shared__ float rinv[B];
    const int jt  = blockIdx.x;       // head
    const int sp  = blockIdx.y;
    const int i0  = sp * IR;
    const int tid = threadIdx.x;

    if (tid < B) {
        float s = 0.f;
#pragma unroll
        for (int kt = 0; kt < 32; ++kt)
            s += psum[((size_t)(tid * 32 + kt)) * NH + jt];
        rinv[tid] = 1.0f / s;
    }
    for (int e = tid; e < B * IR; e += 256) {
        const int b = e / IR, ii = e % IR;
        float v = 0.f;
#pragma unroll
        for (int s2 = 0; s2 < 32; ++s2)
            v += xpart[((size_t)(b * 32 + s2)) * NH * H + (size_t)jt * H + i0 + ii];
        Asl[e] = v;
    }
    __syncthreads();

    const int jl = tid & 63, bg = tid >> 6;
    const int j = jt * 64 + jl;
    const float* wp_ = W + (size_t)i0 * H + j;
    float a0 = 0, a1 = 0, a2 = 0, a3 = 0;
#pragma unroll
    for (int ii = 0; ii < IR; ++ii) {
        const float w = wp_[(size_t)ii * H];
        a0 += w * Asl[(bg * 4 + 0) * IR + ii];
        a1 += w * Asl[(bg * 4 + 1) * IR + ii];
        a2 += w * Asl[(bg * 4 + 2) * IR + ii];
        a3 += w * Asl[(bg * 4 + 3) * IR + ii];
    }
    float* pp = part + ((size_t)sp * B) * H + j;
    pp[(size_t)(bg * 4 + 0) * H] = a0 * rinv[bg * 4 + 0];
    pp[(size_t)(bg * 4 + 1) * H] = a1 * rinv[bg * 4 + 1];
    pp[(size_t)(bg * 4 + 2) * H] = a2 * rinv[bg * 4 + 2];
    pp[(size_t)(bg * 4 + 3) * H] = a3 * rinv[bg * 4 + 3];
}

// ===== LN over sum of partials + bias + residual ============================
template <int ISPL>
__global__ __launch_bounds__(768) void ln_kernel(
        const float* __restrict__ part, const float* __restrict__ bias,
        const float* __restrict__ resid, int residStride,
        const float* __restrict__ g, const float* __restrict__ bet,
        float* __restrict__ out) {
    __shared__ float red[12];
    const int b = blockIdx.x, j = threadIdx.x;
    float v = bias[j] + resid[(size_t)b * residStride + j];
#pragma unroll
    for (int sp = 0; sp < ISPL; ++sp) v += part[((size_t)sp * B + b) * H + j];
    const float mu = blockReduceSum768(v, red) * (1.0f / H);
    const float d  = v - mu;
    const float var = blockReduceSum768(d * d, red) * (1.0f / H);
    out[(size_t)b * H + j] = d * rsqrtf(var + EPS) * g[j] + bet[j];
}

// ===== pooled = tanh(sum_sp part + bp); cls[b] = pooled . wm + bm ===========
template <int ISPL>
__global__ __launch_bounds__(768) void cls_kernel(
        const float* __restrict__ part, const float* __restrict__ bp,
        const float* __restrict__ wm, const float* __restrict__ bm,
        float* __restrict__ out) {
    __shared__ float red[12];
    const int b = blockIdx.x, j = threadIdx.x;
    float v = bp[j];
#pragma unroll
    for (int sp = 0; sp < ISPL; ++sp) v += part[((size_t)sp * B + b) * H + j];
    v = tanhf(v);
    const float s = blockReduceSum768(v * wm[j], red);
    if (j == 0) out[b] = s + bm[0];
}

} // namespace

extern "C" void kernel_launch(void* const* d_in, const int* in_sizes, int n_in,
                              void* d_out, int out_size, void* d_ws, size_t ws_size,
                              hipStream_t stream) {
    const float* x    = (const float*)d_in[0];
    const float* mask = (const float*)d_in[1];
    const float* wq   = (const float*)d_in[2];
    const float* bq   = (const float*)d_in[3];
    const float* wk   = (const float*)d_in[4];
    const float* bk   = (const float*)d_in[5];
    const float* wv   = (const float*)d_in[6];
    const float* bv   = (const float*)d_in[7];
    const float* wo   = (const float*)d_in[8];
    const float* bo   = (const float*)d_in[9];
    const float* ln1g = (const float*)d_in[10];
    const float* ln1b = (const float*)d_in[11];
    const float* w1   = (const float*)d_in[12];
    const float* b1   = (const float*)d_in[13];
    const float* w2   = (const float*)d_in[14];
    const float* b2   = (const float*)d_in[15];
    const float* ln2g = (const float*)d_in[16];
    const float* ln2b = (const float*)d_in[17];
    const float* wp   = (const float*)d_in[18];
    const float* bp   = (const float*)d_in[19];
    const float* wm   = (const float*)d_in[20];
    const float* bm   = (const float*)d_in[21];
    float* out = (float*)d_out;

    // -------- workspace, linear layout (~30 MB) -----------------------------
    float* ws = (float*)d_ws;
    size_t o = 0;
    float* u         = ws + o; o += (size_t)B * NH * H;       // 147456
    float* constk    = ws + o; o += 256;
    float* psum      = ws + o; o += (size_t)B * 32 * NH;      // 6144
    float* attn_out  = ws + o; o += (size_t)B * H;
    float* hidden    = ws + o; o += (size_t)B * H;
    float* xpart     = ws + o; o += (size_t)32 * B * NH * H;  // 4718592
    float* q0_part   = ws + o; o += (size_t)24 * B * H;       // 294912
    float* ctx_part  = ws + o; o += (size_t)24 * B * H;
    float* wo_part   = ws + o; o += (size_t)24 * B * H;
    float* ffn1_part = ws + o; o += (size_t)24 * B * FF;      // 1179648
    float* ffn2_part = ws + o; o += (size_t)48 * B * H;       // 589824
    float* pool_part = ws + o; o += (size_t)24 * B * H;
    (void)ws_size; (void)in_sizes; (void)n_in; (void)out_size;

    // 1) q0 partials = x[:,0,:] @ wq  (288 blocks)
    gemm_partial<H, 24, H><<<dim3(12, 24), 256, 0, stream>>>(x, S * H, wq, q0_part);

    // 2) u[b,h,:] = wk_head @ q0_head (fused q0 reduce + bq); constk  (192 blocks)
    u_kernel<<<B * NH, 256, 0, stream>>>(q0_part, bq, wk, bk, u, constk);

    // 3) scores->exp + row-sum partials + unnormalized xbar partials (512 blocks)
    score_xbar<<<dim3(B, 32), 256, 0, stream>>>(x, u, constk, mask, psum, xpart);

    // 4) ctx partials: normalized xbar per-head slice @ wv  (288 blocks)
    gemm_xpart<24><<<dim3(12, 24), 256, 0, stream>>>(xpart, psum, wv, ctx_part);

    // 5) wo GEMM (fused ctx reduce + bv)  (288 blocks)
    gemm_partial_red<H, 24, H, 24><<<dim3(12, 24), 256, 0, stream>>>(ctx_part, bv, wo, wo_part);

    // 6) LN1 with residual x[:,0,:]  (16 blocks)
    ln_kernel<24><<<B, 768, 0, stream>>>(wo_part, bo, x, S * H, ln1g, ln1b, attn_out);

    // 7) FFN1  (1152 blocks)
    gemm_partial<H, 24, FF><<<dim3(48, 24), 256, 0, stream>>>(attn_out, H, w1, ffn1_part);

    // 8) FFN2 (gelu fused into staging)  (576 blocks)
    gemm_partial_red_gelu<FF, 48, H, 24><<<dim3(12, 48), 256, 0, stream>>>(ffn1_part, b1, w2, ffn2_part);

    // 9) LN2 with residual attn_out  (16 blocks)
    ln_kernel<48><<<B, 768, 0, stream>>>(ffn2_part, b2, attn_out, H, ln2g, ln2b, hidden);

    // 10) pooler partials  (288 blocks)
    gemm_partial<H, 24, H><<<dim3(12, 24), 256, 0, stream>>>(hidden, H, wp, pool_part);

    // 11) classifier  (16 blocks)
    cls_kernel<24><<<B, 768, 0, stream>>>(pool_part, bp, wm, bm, out);
}